// Round 5
// baseline (198.698 us; speedup 1.0000x reference)
//
#include <hip/hip_runtime.h>
#include <cstddef>

#define N_IMG 8
#define B_BOX 1000
#define N_CLS 80
#define C1    81
#define K_MAX 100
#define CAND  (N_CLS * K_MAX)   // 8000
#define BPAD  1024              // padded boxes per class row

typedef unsigned long long u64;

// Exact threshold for fl32(a/b) > 0.5 under RNE:  a/b > 0.5 + 2^-25.
// (double)a > (double)b * CMP is exact: 24-bit x 25-bit significands <= 49 bits.
#define CMP_IOU (0.5 + 0x1p-25)

// ---- DPP wave64 reductions (verified rounds 3-4) --------------------------
template <int CTRL>
__device__ __forceinline__ float dpp_fmax_step(float x, float ident) {
    int o = __builtin_amdgcn_update_dpp(__float_as_int(ident), __float_as_int(x),
                                        CTRL, 0xf, 0xf, false);
    return fmaxf(x, __int_as_float(o));
}
__device__ __forceinline__ float wave_max_bcast(float x, float ident) {
    x = dpp_fmax_step<0x111>(x, ident);
    x = dpp_fmax_step<0x112>(x, ident);
    x = dpp_fmax_step<0x114>(x, ident);
    x = dpp_fmax_step<0x118>(x, ident);
    x = dpp_fmax_step<0x142>(x, ident);
    x = dpp_fmax_step<0x143>(x, ident);
    return __int_as_float(__builtin_amdgcn_readlane(__float_as_int(x), 63));
}
template <int CTRL>
__device__ __forceinline__ int dpp_imin_step(int x, int ident) {
    int o = __builtin_amdgcn_update_dpp(ident, x, CTRL, 0xf, 0xf, false);
    return (o < x) ? o : x;
}
__device__ __forceinline__ int wave_min_bcast(int x, int ident) {
    x = dpp_imin_step<0x111>(x, ident);
    x = dpp_imin_step<0x112>(x, ident);
    x = dpp_imin_step<0x114>(x, ident);
    x = dpp_imin_step<0x118>(x, ident);
    x = dpp_imin_step<0x142>(x, ident);
    x = dpp_imin_step<0x143>(x, ident);
    return __builtin_amdgcn_readlane(x, 63);
}

__device__ __forceinline__ u64 shfl_xor_u64(u64 x, int m) {
    unsigned lo = (unsigned)__shfl_xor((int)(unsigned)(x & 0xffffffffu), m);
    unsigned hi = (unsigned)__shfl_xor((int)(unsigned)(x >> 32), m);
    return ((u64)hi << 32) | lo;
}

// ---- register bitonic network (verified round 4) --------------------------
template <int J>
__device__ __forceinline__ void ice(u64 (&e)[16], int base, int k) {
    #pragma unroll
    for (int t = 0; t < 16; t++) {
        if ((t & J) == 0) {
            const int u_ = t | J;
            bool up = (((base + t) & k) != 0);
            u64 a = e[t], b = e[u_];
            bool sw = up ? (a > b) : (a < b);
            e[t]  = sw ? b : a;
            e[u_] = sw ? a : b;
        }
    }
}
template <int JL>
__device__ __forceinline__ void xce(u64 (&e)[16], int lane, int k) {
    bool lower = ((lane & JL) == 0);
    bool up = ((((lane & ~JL) << 4) & k) != 0);
    bool keepMin = (lower == up);
    #pragma unroll
    for (int t = 0; t < 16; t++) {
        u64 o = shfl_xor_u64(e[t], JL);
        u64 mn = (e[t] < o) ? e[t] : o;
        u64 mx = (e[t] < o) ? o : e[t];
        e[t] = keepMin ? mn : mx;
    }
}
__device__ __forceinline__ void ice_all(u64 (&e)[16], int base, int k) {
    ice<8>(e, base, k); ice<4>(e, base, k); ice<2>(e, base, k); ice<1>(e, base, k);
}

__device__ __forceinline__ float4 decode_box(float4 rr, float4 dd) {
    // identical FP sequence to the verified kernels (contraction blocked)
    float w0 = __fadd_rn(__fsub_rn(rr.w, rr.y), 1.0f);
    float h0 = __fadd_rn(__fsub_rn(rr.z, rr.x), 1.0f);
    float x0 = __fadd_rn(rr.y, __fmul_rn(w0, 0.5f));
    float y0 = __fadd_rn(rr.x, __fmul_rn(h0, 0.5f));
    float tx = __fdiv_rn(dd.x, 10.0f);
    float ty = __fdiv_rn(dd.y, 10.0f);
    float tw = __fdiv_rn(dd.z, 5.0f);
    float th = __fdiv_rn(dd.w, 5.0f);
    float cx = __fadd_rn(__fmul_rn(tx, w0), x0);
    float cy = __fadd_rn(__fmul_rn(ty, h0), y0);
    float ww = __fmul_rn(expf(tw), w0);
    float hh = __fmul_rn(expf(th), h0);
    float xx1 = fminf(fmaxf(__fsub_rn(cx, __fmul_rn(0.5f, ww)), 0.0f), 799.0f);
    float yy1 = fminf(fmaxf(__fsub_rn(cy, __fmul_rn(0.5f, hh)), 0.0f), 799.0f);
    float xx2 = fminf(fmaxf(__fadd_rn(cx, __fmul_rn(0.5f, ww)), 0.0f), 799.0f);
    float yy2 = fminf(fmaxf(__fadd_rn(cy, __fmul_rn(0.5f, hh)), 0.0f), 799.0f);
    return make_float4(yy1, xx1, yy2, xx2);
}

// ---------------------------------------------------------------------------
// Decode/transpose: 128 blocks = (image n, 64-box tile). Reads rois/conf/
// deltas fully coalesced (c fastest), decodes once per (n,b,c), transposes
// through padded LDS, writes class-major boxT/scoreT fully coalesced
// (b fastest). Also copies the rois passthrough output.
// ---------------------------------------------------------------------------
#define CH 40    // classes per half (2 halves of 40 = 80)
__global__ __launch_bounds__(256) void decode_kernel(
    const float* __restrict__ rois,      // [N][B][4]
    const float* __restrict__ conf,      // [N][B][81]
    const float* __restrict__ deltas,    // [N][B][320]
    float* __restrict__ scoreT,          // [N][80][1024]
    float* __restrict__ boxT,            // [N][80][1024][4]
    float* __restrict__ outRois)         // out + 4808
{
    __shared__ float4 lbox[CH][65];      // +1 pad: kills write bank conflicts
    __shared__ float  lsc[CH][65];
    __shared__ float4 lrois[64];

    const int tid  = threadIdx.x;
    const int n    = blockIdx.x >> 4;
    const int tile = blockIdx.x & 15;
    const int b0   = tile * 64;
    const float4 INERT = make_float4(1.0e9f, 1.0e9f, -1.0e9f, -1.0e9f);

    // rois passthrough (independent of the rest)
    {
        int idx = blockIdx.x * 256 + tid;
        if (idx < N_IMG * B_BOX * 4) outRois[idx] = rois[idx];
    }

    if (tid < 64) {
        int b = b0 + tid;
        lrois[tid] = (b < B_BOX) ? ((const float4*)rois)[n * B_BOX + b]
                                 : make_float4(0.f, 0.f, 0.f, 0.f);
    }
    __syncthreads();

    for (int half = 0; half < 2; half++) {
        const int c0 = half * CH;
        // read+decode: flat = bl*CH + cc, c fastest -> coalesced conf/deltas
        #pragma unroll
        for (int i = 0; i < 10; i++) {
            int flat = tid + i * 256;          // 2560 = 64*40
            int bl = flat / CH, cc = flat - bl * CH;
            int b = b0 + bl, c = c0 + cc;
            float4 bx; float sc;
            if (b < B_BOX) {
                float4 dd = ((const float4*)deltas)[(n * B_BOX + b) * N_CLS + c];
                sc = conf[((size_t)(n * B_BOX + b)) * C1 + c];
                bx = decode_box(lrois[bl], dd);
            } else {
                bx = INERT; sc = 0.0f;         // sentinel: invalid
            }
            lbox[cc][bl] = bx; lsc[cc][bl] = sc;
        }
        __syncthreads();
        // write: flat = cc*64 + bl, b fastest -> coalesced boxT/scoreT
        #pragma unroll
        for (int i = 0; i < 10; i++) {
            int flat = tid + i * 256;
            int cc = flat >> 6, bl = flat & 63;
            int c = c0 + cc;
            size_t row = ((size_t)n * N_CLS + c) * BPAD + b0 + bl;
            ((float4*)boxT)[row] = lbox[cc][bl];
            scoreT[row] = lsc[cc][bl];
        }
        __syncthreads();
    }
}

// ---------------------------------------------------------------------------
// NMS: one wave per (image, class). PRE=true: phase 1 loads pre-decoded,
// coalesced boxT/scoreT. PRE=false: verified round-4 self-decoding fallback.
// Phases 2-4 identical to the verified round-4 kernel.
// ---------------------------------------------------------------------------
template <bool PRE>
__global__ __launch_bounds__(64) void nms_kernel(
    const float* __restrict__ rois,
    const float* __restrict__ conf,
    const float* __restrict__ deltas,
    const float* __restrict__ scoreT,    // PRE only
    const float* __restrict__ boxT,      // PRE only
    float* __restrict__ candScore,       // [N][CAND]
    float* __restrict__ candBox)         // [N][CAND][4]
{
    __shared__ float4 sbox[1024];
    __shared__ u64    skeyS[1026];
    __shared__ float4 sboxS[1026];

    const int n    = blockIdx.x / N_CLS;
    const int c    = blockIdx.x % N_CLS;
    const int lane = threadIdx.x;
    const int base = lane * 16;
    const float4 INERT = make_float4(1.0e9f, 1.0e9f, -1.0e9f, -1.0e9f);

    u64 e[16];

    if (PRE) {
        const size_t row = ((size_t)n * N_CLS + c) * BPAD;
        #pragma unroll
        for (int t = 0; t < 16; t++) {
            const int b = lane + t * 64;               // coalesced
            float4 q = ((const float4*)boxT)[row + b];
            float sc = scoreT[row + b];
            sbox[b] = q;
            unsigned sb = (sc > 0.05f) ? __float_as_uint(sc) : 0u;
            e[t] = ((u64)sb << 32) | (unsigned)(1023 - b);
        }
    } else {
        #pragma unroll
        for (int t = 0; t < 16; t++) {
            const int b = base + t;
            if (b < B_BOX) {
                float4 rr = ((const float4*)rois)[n * B_BOX + b];
                float4 dd = ((const float4*)deltas)[(n * B_BOX + b) * N_CLS + c];
                float score = conf[((size_t)(n * B_BOX + b)) * C1 + c];
                float4 q = decode_box(rr, dd);
                sbox[b] = q;
                unsigned sb = (score > 0.05f) ? __float_as_uint(score) : 0u;
                e[t] = ((u64)sb << 32) | (unsigned)(1023 - b);
            } else {
                sbox[b] = INERT;
                e[t] = (u64)(unsigned)(1023 - b);
            }
        }
    }

    // --- phase 2: bitonic sort, descending -----------------------------------
    ice<1>(e, base, 2);
    ice<2>(e, base, 4);  ice<1>(e, base, 4);
    ice<4>(e, base, 8);  ice<2>(e, base, 8);  ice<1>(e, base, 8);
    ice_all(e, base, 16);
    xce<1>(e, lane, 32);  ice_all(e, base, 32);
    xce<2>(e, lane, 64);  xce<1>(e, lane, 64);  ice_all(e, base, 64);
    xce<4>(e, lane, 128); xce<2>(e, lane, 128); xce<1>(e, lane, 128); ice_all(e, base, 128);
    xce<8>(e, lane, 256); xce<4>(e, lane, 256); xce<2>(e, lane, 256); xce<1>(e, lane, 256);
    ice_all(e, base, 256);
    xce<16>(e, lane, 512); xce<8>(e, lane, 512); xce<4>(e, lane, 512); xce<2>(e, lane, 512);
    xce<1>(e, lane, 512);  ice_all(e, base, 512);
    xce<32>(e, lane, 1024); xce<16>(e, lane, 1024); xce<8>(e, lane, 1024);
    xce<4>(e, lane, 1024);  xce<2>(e, lane, 1024);  xce<1>(e, lane, 1024);
    ice_all(e, base, 1024);

    #pragma unroll
    for (int t = 0; t < 16; t++) skeyS[base + t] = e[t];
    if (lane < 2) { skeyS[1024 + lane] = 0; sboxS[1024 + lane] = INERT; }
    __syncthreads();

    // --- phase 3: boxes into sorted order ------------------------------------
    for (int p = lane; p < 1024; p += 64) {
        u64 key = skeyS[p];
        int b = 1023 - (int)(unsigned)(key & 0xffffffffu);
        sboxS[p] = sbox[b];
    }
    __syncthreads();

    // --- phase 4: greedy scan (verified round 4) -----------------------------
    float* myScore = candScore + (size_t)n * CAND + c * K_MAX;
    float* myBox   = candBox   + ((size_t)n * CAND + c * K_MAX) * 4;

    float4 kb0 = INERT, kb1 = INERT;
    float  ka0 = 0.0f,  ka1 = 0.0f;
    int cnt = 0;

    u64    kcur = skeyS[0], knxt = skeyS[1];
    float4 bcur = sboxS[0], bnxt = sboxS[1];

    for (int j = 0; j < 1024; j++) {
        if (!(kcur >> 32)) break;
        u64    k2 = skeyS[j + 2];
        float4 b2 = sboxS[j + 2];

        const float4 cb = bcur;
        const float  sc = __uint_as_float((unsigned)(kcur >> 32));
        const float  carea = __fmul_rn(__fsub_rn(cb.z, cb.x), __fsub_rn(cb.w, cb.y));

        float iy1a = fmaxf(kb0.x, cb.x), ix1a = fmaxf(kb0.y, cb.y);
        float iy2a = fminf(kb0.z, cb.z), ix2a = fminf(kb0.w, cb.w);
        float iha  = fmaxf(__fsub_rn(iy2a, iy1a), 0.0f);
        float iwa  = fmaxf(__fsub_rn(ix2a, ix1a), 0.0f);
        float intA = __fmul_rn(iha, iwa);
        float denA = fmaxf(__fsub_rn(__fadd_rn(ka0, carea), intA), 1e-8f);
        bool supA  = (double)intA > (double)denA * CMP_IOU;

        float iy1b = fmaxf(kb1.x, cb.x), ix1b = fmaxf(kb1.y, cb.y);
        float iy2b = fminf(kb1.z, cb.z), ix2b = fminf(kb1.w, cb.w);
        float ihb  = fmaxf(__fsub_rn(iy2b, iy1b), 0.0f);
        float iwb  = fmaxf(__fsub_rn(ix2b, ix1b), 0.0f);
        float intB = __fmul_rn(ihb, iwb);
        float denB = fmaxf(__fsub_rn(__fadd_rn(ka1, carea), intB), 1e-8f);
        bool supB  = (double)intB > (double)denB * CMP_IOU;

        u64 m = __ballot(supA || supB);
        if (m == 0) {
            if (lane == (cnt & 63)) {
                if (cnt < 64) { kb0 = cb; ka0 = carea; }
                else          { kb1 = cb; ka1 = carea; }
                myScore[cnt] = sc;
                ((float4*)myBox)[cnt] = cb;
            }
            cnt++;
            if (cnt >= K_MAX) break;
        }
        kcur = knxt; knxt = k2;
        bcur = bnxt; bnxt = b2;
    }
    for (int q = cnt + lane; q < K_MAX; q += 64) myScore[q] = -1.0f;
}

// ---------------------------------------------------------------------------
// Top-K merge (verified round 4, unchanged).
// ---------------------------------------------------------------------------
__global__ __launch_bounds__(64) void topk_kernel(
    const float* __restrict__ candScore,
    const float* __restrict__ candBox,
    float* __restrict__ out)
{
    __shared__ float selV[K_MAX];
    __shared__ int   selFi[K_MAX];

    const int n    = blockIdx.x;
    const int lane = threadIdx.x;
    const float SENT = -3.0e38f;
    const float* S = candScore + (size_t)n * CAND;

    const int  c0   = lane;
    const int  c1   = lane + 64;
    const bool has1 = (c1 < N_CLS);

    int h0 = 0, h1 = 0;
    float cur0 = S[c0 * K_MAX + 0];
    float nxt0 = S[c0 * K_MAX + 1];
    float cur1 = has1 ? S[c1 * K_MAX + 0] : SENT;
    float nxt1 = has1 ? S[c1 * K_MAX + 1] : SENT;

    int K = 0;
    for (int k = 0; k < K_MAX; k++) {
        float lv; int lfi;
        if (cur1 > cur0) { lv = cur1; lfi = c1 * K_MAX + h1; }
        else             { lv = cur0; lfi = c0 * K_MAX + h0; }

        float M = wave_max_bcast(lv, SENT);
        if (!(M > 0.0f)) break;

        u64 m = __ballot(lv == M);
        int fi;
        if (__popcll(m) == 1) {
            fi = __builtin_amdgcn_readlane(lfi, __ffsll(m) - 1);
        } else {
            int cnd = (lv == M) ? lfi : 0x7fffffff;
            fi = wave_min_bcast(cnd, 0x7fffffff);
        }

        if (fi == c0 * K_MAX + h0) {
            h0++; cur0 = nxt0;
            nxt0 = (h0 + 1 < K_MAX) ? S[c0 * K_MAX + h0 + 1] : SENT;
        } else if (has1 && fi == c1 * K_MAX + h1) {
            h1++; cur1 = nxt1;
            nxt1 = (h1 + 1 < K_MAX) ? S[c1 * K_MAX + h1 + 1] : SENT;
        }

        if (lane == 0) { selV[k] = M; selFi[k] = fi; }
        K++;
    }
    __syncthreads();

    for (int q = lane; q < K_MAX; q += 64) {
        if (q < K) {
            int   fi = selFi[q];
            float v  = selV[q];
            float4 bx = *((const float4*)(candBox + ((size_t)n * CAND + fi) * 4));
            ((float4*)out)[n * K_MAX + q] = bx;
            out[N_IMG * K_MAX * 4 + n * K_MAX + q] = v;
            out[N_IMG * K_MAX * 5 + n * K_MAX + q] = (float)(fi / K_MAX);
        } else {
            ((float4*)out)[n * K_MAX + q] = make_float4(0.0f, 0.0f, 0.0f, 0.0f);
            out[N_IMG * K_MAX * 4 + n * K_MAX + q] = 0.0f;
            out[N_IMG * K_MAX * 5 + n * K_MAX + q] = 0.0f;
        }
    }
    if (lane == 0) out[N_IMG * K_MAX * 6 + n] = (float)K;
}

extern "C" void kernel_launch(void* const* d_in, const int* in_sizes, int n_in,
                              void* d_out, int out_size, void* d_ws, size_t ws_size,
                              hipStream_t stream) {
    const float* rois   = (const float*)d_in[0];   // [8][1000][4]
    const float* conf   = (const float*)d_in[1];   // [8][1000][81]
    const float* deltas = (const float*)d_in[2];   // [8][1000][320]
    float* out = (float*)d_out;                    // 36808 floats
    float* ws  = (float*)d_ws;

    float* candScore = ws;                                      // 64000 f
    float* candBox   = candScore + (size_t)N_IMG * CAND;        // 256000 f
    float* scoreT    = candBox + (size_t)N_IMG * CAND * 4;      // 655360 f
    float* boxT      = scoreT + (size_t)N_IMG * N_CLS * BPAD;   // 2621440 f
    const size_t needed = ((size_t)N_IMG * CAND * 5
                         + (size_t)N_IMG * N_CLS * BPAD * 5) * sizeof(float);

    if (ws_size >= needed) {
        decode_kernel<<<N_IMG * 16, 256, 0, stream>>>(
            rois, conf, deltas, scoreT, boxT, out + 4808);
        nms_kernel<true><<<N_IMG * N_CLS, 64, 0, stream>>>(
            rois, conf, deltas, scoreT, boxT, candScore, candBox);
        topk_kernel<<<N_IMG, 64, 0, stream>>>(candScore, candBox, out);
    } else {
        nms_kernel<false><<<N_IMG * N_CLS, 64, 0, stream>>>(
            rois, conf, deltas, nullptr, nullptr, candScore, candBox);
        topk_kernel<<<N_IMG, 64, 0, stream>>>(candScore, candBox, out);
        hipMemcpyAsync(out + 4808, rois,
                       (size_t)N_IMG * B_BOX * 4 * sizeof(float),
                       hipMemcpyDeviceToDevice, stream);
    }
}

// Round 6
// 182.527 us; speedup vs baseline: 1.0886x; 1.0886x over previous
//
#include <hip/hip_runtime.h>
#include <cstddef>

#define N_IMG 8
#define B_BOX 1000
#define N_CLS 80
#define C1    81
#define K_MAX 100
#define CAND  (N_CLS * K_MAX)   // 8000
#define BPAD  1024              // padded boxes per class row

typedef unsigned long long u64;

// Exact threshold for fl32(a/b) > 0.5 under RNE:  a/b > 0.5 + 2^-25.
// (double)a > (double)b * CMP is exact: 24-bit x 25-bit significands <= 49 bits.
#define CMP_IOU (0.5 + 0x1p-25)

__device__ __forceinline__ u64 shfl_xor_u64(u64 x, int m) {
    unsigned lo = (unsigned)__shfl_xor((int)(unsigned)(x & 0xffffffffu), m);
    unsigned hi = (unsigned)__shfl_xor((int)(unsigned)(x >> 32), m);
    return ((u64)hi << 32) | lo;
}

// ---- register bitonic network (verified rounds 4-5) -----------------------
template <int J>
__device__ __forceinline__ void ice(u64 (&e)[16], int base, int k) {
    #pragma unroll
    for (int t = 0; t < 16; t++) {
        if ((t & J) == 0) {
            const int u_ = t | J;
            bool up = (((base + t) & k) != 0);
            u64 a = e[t], b = e[u_];
            bool sw = up ? (a > b) : (a < b);
            e[t]  = sw ? b : a;
            e[u_] = sw ? a : b;
        }
    }
}
template <int JL>
__device__ __forceinline__ void xce(u64 (&e)[16], int lane, int k) {
    bool lower = ((lane & JL) == 0);
    bool up = ((((lane & ~JL) << 4) & k) != 0);
    bool keepMin = (lower == up);
    #pragma unroll
    for (int t = 0; t < 16; t++) {
        u64 o = shfl_xor_u64(e[t], JL);
        u64 mn = (e[t] < o) ? e[t] : o;
        u64 mx = (e[t] < o) ? o : e[t];
        e[t] = keepMin ? mn : mx;
    }
}
__device__ __forceinline__ void ice_all(u64 (&e)[16], int base, int k) {
    ice<8>(e, base, k); ice<4>(e, base, k); ice<2>(e, base, k); ice<1>(e, base, k);
}

__device__ __forceinline__ float4 decode_box(float4 rr, float4 dd) {
    // identical FP sequence to the verified kernels (contraction blocked)
    float w0 = __fadd_rn(__fsub_rn(rr.w, rr.y), 1.0f);
    float h0 = __fadd_rn(__fsub_rn(rr.z, rr.x), 1.0f);
    float x0 = __fadd_rn(rr.y, __fmul_rn(w0, 0.5f));
    float y0 = __fadd_rn(rr.x, __fmul_rn(h0, 0.5f));
    float tx = __fdiv_rn(dd.x, 10.0f);
    float ty = __fdiv_rn(dd.y, 10.0f);
    float tw = __fdiv_rn(dd.z, 5.0f);
    float th = __fdiv_rn(dd.w, 5.0f);
    float cx = __fadd_rn(__fmul_rn(tx, w0), x0);
    float cy = __fadd_rn(__fmul_rn(ty, h0), y0);
    float ww = __fmul_rn(expf(tw), w0);
    float hh = __fmul_rn(expf(th), h0);
    float xx1 = fminf(fmaxf(__fsub_rn(cx, __fmul_rn(0.5f, ww)), 0.0f), 799.0f);
    float yy1 = fminf(fmaxf(__fsub_rn(cy, __fmul_rn(0.5f, hh)), 0.0f), 799.0f);
    float xx2 = fminf(fmaxf(__fadd_rn(cx, __fmul_rn(0.5f, ww)), 0.0f), 799.0f);
    float yy2 = fminf(fmaxf(__fadd_rn(cy, __fmul_rn(0.5f, hh)), 0.0f), 799.0f);
    return make_float4(yy1, xx1, yy2, xx2);
}

// ---------------------------------------------------------------------------
// Decode/transpose v2: 504 blocks = (image, 16-box tile). Fully coalesced
// reads (deltas: 16x16B contiguous per box; conf: 64B per box), transpose via
// small LDS, coalesced 256B writes. Pads rows [1000,1024). Folds in the rois
// passthrough copy.
// ---------------------------------------------------------------------------
#define TILE  16
#define NTILE 63    // ceil(1000/16)
__global__ __launch_bounds__(256) void decode_kernel(
    const float* __restrict__ rois,      // [N][B][4]
    const float* __restrict__ conf,      // [N][B][81]
    const float* __restrict__ deltas,    // [N][B][320]
    float* __restrict__ scoreT,          // [N][80][1024]
    float* __restrict__ boxT,            // [N][80][1024][4]
    float* __restrict__ outRois)         // out + 4808
{
    __shared__ float4 lrois[TILE];
    __shared__ float4 lbox[16][TILE + 1];
    __shared__ float  lsc[16][TILE + 1];

    const int tid  = threadIdx.x;
    const int n    = blockIdx.x / NTILE;
    const int tile = blockIdx.x % NTILE;
    const int b0   = tile * TILE;
    const float4 INERT = make_float4(1.0e9f, 1.0e9f, -1.0e9f, -1.0e9f);

    // rois passthrough
    {
        int gidx = blockIdx.x * 256 + tid;
        if (gidx < N_IMG * B_BOX * 4) outRois[gidx] = rois[gidx];
    }

    if (tid < TILE) {
        int b = b0 + tid;
        lrois[tid] = (b < B_BOX) ? ((const float4*)rois)[n * B_BOX + b]
                                 : make_float4(0.f, 0.f, 0.f, 0.f);
    }
    __syncthreads();

    #pragma unroll
    for (int c0 = 0; c0 < N_CLS; c0 += 16) {
        {   // load+decode: ci fastest -> contiguous 256B deltas / 64B conf per box
            int bl = tid >> 4, ci = tid & 15;
            int b = b0 + bl, c = c0 + ci;
            float4 bx; float sc;
            if (b < B_BOX) {
                float4 dd = ((const float4*)deltas)[(n * B_BOX + b) * N_CLS + c];
                sc = conf[((size_t)(n * B_BOX + b)) * C1 + c];
                bx = decode_box(lrois[bl], dd);
            } else { bx = INERT; sc = 0.0f; }
            lbox[ci][bl] = bx; lsc[ci][bl] = sc;
        }
        __syncthreads();
        {   // write: bl fastest -> contiguous 256B boxT / 64B scoreT per class
            int cc = tid >> 4, bl = tid & 15;
            size_t row = ((size_t)n * N_CLS + c0 + cc) * BPAD + b0 + bl;
            ((float4*)boxT)[row] = lbox[cc][bl];
            scoreT[row] = lsc[cc][bl];
        }
        __syncthreads();
    }

    // padding rows b in [1008, 1024) (tiles cover up to 1008)
    if (tile == 0) {
        for (int i = tid; i < N_CLS * 16; i += 256) {
            int c = i >> 4, b = 1008 + (i & 15);
            size_t row = ((size_t)n * N_CLS + c) * BPAD + b;
            ((float4*)boxT)[row] = INERT;
            scoreT[row] = 0.0f;
        }
    }
}

// ---------------------------------------------------------------------------
// NMS (verified round 5, unchanged): one wave per (image, class); register
// bitonic sort of (score,idx) keys; greedy scan == reference sequential
// argmax. PRE=true reads decoded boxT/scoreT; PRE=false self-decodes.
// ---------------------------------------------------------------------------
template <bool PRE>
__global__ __launch_bounds__(64) void nms_kernel(
    const float* __restrict__ rois,
    const float* __restrict__ conf,
    const float* __restrict__ deltas,
    const float* __restrict__ scoreT,
    const float* __restrict__ boxT,
    float* __restrict__ candScore,       // [N][CAND]
    float* __restrict__ candBox)         // [N][CAND][4]
{
    __shared__ float4 sbox[1024];
    __shared__ u64    skeyS[1026];
    __shared__ float4 sboxS[1026];

    const int n    = blockIdx.x / N_CLS;
    const int c    = blockIdx.x % N_CLS;
    const int lane = threadIdx.x;
    const int base = lane * 16;
    const float4 INERT = make_float4(1.0e9f, 1.0e9f, -1.0e9f, -1.0e9f);

    u64 e[16];

    if (PRE) {
        const size_t row = ((size_t)n * N_CLS + c) * BPAD;
        #pragma unroll
        for (int t = 0; t < 16; t++) {
            const int b = lane + t * 64;               // coalesced
            float4 q = ((const float4*)boxT)[row + b];
            float sc = scoreT[row + b];
            sbox[b] = q;
            unsigned sb = (sc > 0.05f) ? __float_as_uint(sc) : 0u;
            e[t] = ((u64)sb << 32) | (unsigned)(1023 - b);
        }
    } else {
        #pragma unroll
        for (int t = 0; t < 16; t++) {
            const int b = base + t;
            if (b < B_BOX) {
                float4 rr = ((const float4*)rois)[n * B_BOX + b];
                float4 dd = ((const float4*)deltas)[(n * B_BOX + b) * N_CLS + c];
                float score = conf[((size_t)(n * B_BOX + b)) * C1 + c];
                float4 q = decode_box(rr, dd);
                sbox[b] = q;
                unsigned sb = (score > 0.05f) ? __float_as_uint(score) : 0u;
                e[t] = ((u64)sb << 32) | (unsigned)(1023 - b);
            } else {
                sbox[b] = INERT;
                e[t] = (u64)(unsigned)(1023 - b);
            }
        }
    }

    // bitonic sort, descending
    ice<1>(e, base, 2);
    ice<2>(e, base, 4);  ice<1>(e, base, 4);
    ice<4>(e, base, 8);  ice<2>(e, base, 8);  ice<1>(e, base, 8);
    ice_all(e, base, 16);
    xce<1>(e, lane, 32);  ice_all(e, base, 32);
    xce<2>(e, lane, 64);  xce<1>(e, lane, 64);  ice_all(e, base, 64);
    xce<4>(e, lane, 128); xce<2>(e, lane, 128); xce<1>(e, lane, 128); ice_all(e, base, 128);
    xce<8>(e, lane, 256); xce<4>(e, lane, 256); xce<2>(e, lane, 256); xce<1>(e, lane, 256);
    ice_all(e, base, 256);
    xce<16>(e, lane, 512); xce<8>(e, lane, 512); xce<4>(e, lane, 512); xce<2>(e, lane, 512);
    xce<1>(e, lane, 512);  ice_all(e, base, 512);
    xce<32>(e, lane, 1024); xce<16>(e, lane, 1024); xce<8>(e, lane, 1024);
    xce<4>(e, lane, 1024);  xce<2>(e, lane, 1024);  xce<1>(e, lane, 1024);
    ice_all(e, base, 1024);

    #pragma unroll
    for (int t = 0; t < 16; t++) skeyS[base + t] = e[t];
    if (lane < 2) { skeyS[1024 + lane] = 0; sboxS[1024 + lane] = INERT; }
    __syncthreads();

    for (int p = lane; p < 1024; p += 64) {
        u64 key = skeyS[p];
        int b = 1023 - (int)(unsigned)(key & 0xffffffffu);
        sboxS[p] = sbox[b];
    }
    __syncthreads();

    // greedy scan
    float* myScore = candScore + (size_t)n * CAND + c * K_MAX;
    float* myBox   = candBox   + ((size_t)n * CAND + c * K_MAX) * 4;

    float4 kb0 = INERT, kb1 = INERT;
    float  ka0 = 0.0f,  ka1 = 0.0f;
    int cnt = 0;

    u64    kcur = skeyS[0], knxt = skeyS[1];
    float4 bcur = sboxS[0], bnxt = sboxS[1];

    for (int j = 0; j < 1024; j++) {
        if (!(kcur >> 32)) break;
        u64    k2 = skeyS[j + 2];
        float4 b2 = sboxS[j + 2];

        const float4 cb = bcur;
        const float  sc = __uint_as_float((unsigned)(kcur >> 32));
        const float  carea = __fmul_rn(__fsub_rn(cb.z, cb.x), __fsub_rn(cb.w, cb.y));

        float iy1a = fmaxf(kb0.x, cb.x), ix1a = fmaxf(kb0.y, cb.y);
        float iy2a = fminf(kb0.z, cb.z), ix2a = fminf(kb0.w, cb.w);
        float iha  = fmaxf(__fsub_rn(iy2a, iy1a), 0.0f);
        float iwa  = fmaxf(__fsub_rn(ix2a, ix1a), 0.0f);
        float intA = __fmul_rn(iha, iwa);
        float denA = fmaxf(__fsub_rn(__fadd_rn(ka0, carea), intA), 1e-8f);
        bool supA  = (double)intA > (double)denA * CMP_IOU;

        float iy1b = fmaxf(kb1.x, cb.x), ix1b = fmaxf(kb1.y, cb.y);
        float iy2b = fminf(kb1.z, cb.z), ix2b = fminf(kb1.w, cb.w);
        float ihb  = fmaxf(__fsub_rn(iy2b, iy1b), 0.0f);
        float iwb  = fmaxf(__fsub_rn(ix2b, ix1b), 0.0f);
        float intB = __fmul_rn(ihb, iwb);
        float denB = fmaxf(__fsub_rn(__fadd_rn(ka1, carea), intB), 1e-8f);
        bool supB  = (double)intB > (double)denB * CMP_IOU;

        u64 m = __ballot(supA || supB);
        if (m == 0) {
            if (lane == (cnt & 63)) {
                if (cnt < 64) { kb0 = cb; ka0 = carea; }
                else          { kb1 = cb; ka1 = carea; }
                myScore[cnt] = sc;
                ((float4*)myBox)[cnt] = cb;
            }
            cnt++;
            if (cnt >= K_MAX) break;
        }
        kcur = knxt; knxt = k2;
        bcur = bnxt; bnxt = b2;
    }
    for (int q = cnt + lane; q < K_MAX; q += 64) myScore[q] = -1.0f;
}

// ---------------------------------------------------------------------------
// Top-K v2: exact parallel MSD radix-select per image (256 threads).
// Composite key K(q) = (score_bits << 13) | (8191 - q): unique, 44 bits,
// descending K order == (score desc, flat index asc) — exactly lax.top_k's
// stable order, including the -1 invalid tail (score_bits=0, index asc).
// 4 passes x 11 bits find the exact 100th-largest key T; compact K >= T
// (exactly 100 by uniqueness); rank by pairwise compare; write outputs.
// ---------------------------------------------------------------------------
__global__ __launch_bounds__(256) void topk_kernel(
    const float* __restrict__ candScore,
    const float* __restrict__ candBox,
    float* __restrict__ out)
{
    __shared__ unsigned U[CAND];        // 32 KB: score bits (0 if invalid)
    __shared__ int  hist[2048];
    __shared__ int  psum[256];
    __shared__ u64  selK[K_MAX];
    __shared__ int  selQ[K_MAX];
    __shared__ int  nsel, sB, sR, cntv;

    const int n   = blockIdx.x;
    const int tid = threadIdx.x;
    const float* S = candScore + (size_t)n * CAND;

    for (int i = tid; i < CAND; i += 256) {
        float s = S[i];
        U[i] = (s > 0.0f) ? __float_as_uint(s) : 0u;   // valid scores are > 0.05
    }
    if (tid == 0) { nsel = 0; cntv = 0; }
    __syncthreads();

    u64 pref = 0;
    int r = K_MAX;

    #pragma unroll
    for (int pass = 0; pass < 4; pass++) {
        const int shift = 33 - 11 * pass;
        for (int j = tid; j < 2048; j += 256) hist[j] = 0;
        __syncthreads();

        for (int i = tid; i < CAND; i += 256) {
            u64 K = (((u64)U[i]) << 13) | (unsigned)(8191 - i);
            if ((K >> (shift + 11)) == pref)
                atomicAdd(&hist[(int)((K >> shift) & 0x7FF)], 1);
        }
        __syncthreads();

        // group sums from top: group t covers bins [2047-8t-7 .. 2047-8t]
        {
            int g = 0;
            #pragma unroll
            for (int j = 0; j < 8; j++) g += hist[2047 - 8 * tid - j];
            psum[tid] = g;
        }
        __syncthreads();
        for (int off = 1; off < 256; off <<= 1) {   // inclusive scan
            int v = (tid >= off) ? psum[tid - off] : 0;
            __syncthreads();
            psum[tid] += v;
            __syncthreads();
        }
        {
            int before = (tid > 0) ? psum[tid - 1] : 0;
            if (before < r && psum[tid] >= r) {      // unique thread
                int acc = before;
                #pragma unroll
                for (int j = 0; j < 8; j++) {
                    int b = 2047 - 8 * tid - j;
                    int h = hist[b];
                    acc += h;
                    if (acc >= r) { sB = b; sR = r - (acc - h); break; }
                }
            }
        }
        __syncthreads();
        pref = (pref << 11) | (unsigned)sB;
        r = sR;
        __syncthreads();
    }
    const u64 T64 = pref;   // exact rank-100 key

    for (int i = tid; i < CAND; i += 256) {
        u64 K = (((u64)U[i]) << 13) | (unsigned)(8191 - i);
        if (K >= T64) {
            int s = atomicAdd(&nsel, 1);    // exactly K_MAX selected
            selK[s] = K; selQ[s] = i;
        }
    }
    __syncthreads();

    if (tid < K_MAX) {
        const u64 Ki = selK[tid];
        int rank = 0;
        for (int j = 0; j < K_MAX; j++) rank += (selK[j] > Ki) ? 1 : 0;

        const unsigned u = (unsigned)(Ki >> 13);
        const int q = selQ[tid];
        const bool valid = (u != 0);
        float4 bx = make_float4(0.f, 0.f, 0.f, 0.f);
        if (valid) bx = ((const float4*)candBox)[(size_t)n * CAND + q];

        ((float4*)out)[n * K_MAX + rank] = bx;
        out[N_IMG * K_MAX * 4 + n * K_MAX + rank] = valid ? __uint_as_float(u) : 0.0f;
        out[N_IMG * K_MAX * 5 + n * K_MAX + rank] = valid ? (float)(q / K_MAX) : 0.0f;
        if (valid) atomicAdd(&cntv, 1);
    }
    __syncthreads();
    if (tid == 0) out[N_IMG * K_MAX * 6 + n] = (float)cntv;
}

extern "C" void kernel_launch(void* const* d_in, const int* in_sizes, int n_in,
                              void* d_out, int out_size, void* d_ws, size_t ws_size,
                              hipStream_t stream) {
    const float* rois   = (const float*)d_in[0];   // [8][1000][4]
    const float* conf   = (const float*)d_in[1];   // [8][1000][81]
    const float* deltas = (const float*)d_in[2];   // [8][1000][320]
    float* out = (float*)d_out;                    // 36808 floats
    float* ws  = (float*)d_ws;

    float* candScore = ws;                                      // 64000 f
    float* candBox   = candScore + (size_t)N_IMG * CAND;        // 256000 f
    float* scoreT    = candBox + (size_t)N_IMG * CAND * 4;      // 655360 f
    float* boxT      = scoreT + (size_t)N_IMG * N_CLS * BPAD;   // 2621440 f
    const size_t needed = ((size_t)N_IMG * CAND * 5
                         + (size_t)N_IMG * N_CLS * BPAD * 5) * sizeof(float);

    if (ws_size >= needed) {
        decode_kernel<<<N_IMG * NTILE, 256, 0, stream>>>(
            rois, conf, deltas, scoreT, boxT, out + 4808);
        nms_kernel<true><<<N_IMG * N_CLS, 64, 0, stream>>>(
            rois, conf, deltas, scoreT, boxT, candScore, candBox);
        topk_kernel<<<N_IMG, 256, 0, stream>>>(candScore, candBox, out);
    } else {
        nms_kernel<false><<<N_IMG * N_CLS, 64, 0, stream>>>(
            rois, conf, deltas, nullptr, nullptr, candScore, candBox);
        topk_kernel<<<N_IMG, 256, 0, stream>>>(candScore, candBox, out);
        hipMemcpyAsync(out + 4808, rois,
                       (size_t)N_IMG * B_BOX * 4 * sizeof(float),
                       hipMemcpyDeviceToDevice, stream);
    }
}

// Round 7
// 180.661 us; speedup vs baseline: 1.0998x; 1.0103x over previous
//
#include <hip/hip_runtime.h>
#include <cstddef>

#define N_IMG 8
#define B_BOX 1000
#define N_CLS 80
#define C1    81
#define K_MAX 100
#define CAND  (N_CLS * K_MAX)   // 8000
#define BPAD  1024              // padded boxes per class row

typedef unsigned long long u64;

// Exact threshold for fl32(a/b) > 0.5 under RNE:  a/b > 0.5 + 2^-25.
// (double)a > (double)b * CMP is exact: 24-bit x 25-bit significands <= 49 bits.
#define CMP_IOU (0.5 + 0x1p-25)

__device__ __forceinline__ u64 shfl_xor_u64(u64 x, int m) {
    unsigned lo = (unsigned)__shfl_xor((int)(unsigned)(x & 0xffffffffu), m);
    unsigned hi = (unsigned)__shfl_xor((int)(unsigned)(x >> 32), m);
    return ((u64)hi << 32) | lo;
}

// XOR-lane exchange: DPP quad_perm for 1,2; ds_swizzle bit-mode for 4,8,16
// (offset = xor<<10 | 0x1F); bpermute only for 32. Same data movement as
// __shfl_xor, cheaper instruction class.
template <int MASK>
__device__ __forceinline__ unsigned xor_lane32(unsigned x) {
    if constexpr (MASK == 1)
        return (unsigned)__builtin_amdgcn_update_dpp((int)x, (int)x, 0xB1, 0xF, 0xF, false);
    else if constexpr (MASK == 2)
        return (unsigned)__builtin_amdgcn_update_dpp((int)x, (int)x, 0x4E, 0xF, 0xF, false);
    else
        return (unsigned)__builtin_amdgcn_ds_swizzle((int)x, (0x1F | (MASK << 10)));
}
template <int JL>
__device__ __forceinline__ u64 xor_u64(u64 x) {
    if constexpr (JL == 32) {
        return shfl_xor_u64(x, 32);
    } else {
        unsigned lo = xor_lane32<JL>((unsigned)(x & 0xffffffffu));
        unsigned hi = xor_lane32<JL>((unsigned)(x >> 32));
        return ((u64)hi << 32) | lo;
    }
}

// ---- register bitonic network (verified rounds 4-6; exchange prim swapped) --
template <int J>
__device__ __forceinline__ void ice(u64 (&e)[16], int base, int k) {
    #pragma unroll
    for (int t = 0; t < 16; t++) {
        if ((t & J) == 0) {
            const int u_ = t | J;
            bool up = (((base + t) & k) != 0);
            u64 a = e[t], b = e[u_];
            bool sw = up ? (a > b) : (a < b);
            e[t]  = sw ? b : a;
            e[u_] = sw ? a : b;
        }
    }
}
template <int JL>
__device__ __forceinline__ void xce(u64 (&e)[16], int lane, int k) {
    bool lower = ((lane & JL) == 0);
    bool up = ((((lane & ~JL) << 4) & k) != 0);
    bool keepMin = (lower == up);
    #pragma unroll
    for (int t = 0; t < 16; t++) {
        u64 o = xor_u64<JL>(e[t]);
        u64 mn = (e[t] < o) ? e[t] : o;
        u64 mx = (e[t] < o) ? o : e[t];
        e[t] = keepMin ? mn : mx;
    }
}
__device__ __forceinline__ void ice_all(u64 (&e)[16], int base, int k) {
    ice<8>(e, base, k); ice<4>(e, base, k); ice<2>(e, base, k); ice<1>(e, base, k);
}

__device__ __forceinline__ float4 decode_box(float4 rr, float4 dd) {
    // identical FP sequence to the verified kernels (contraction blocked)
    float w0 = __fadd_rn(__fsub_rn(rr.w, rr.y), 1.0f);
    float h0 = __fadd_rn(__fsub_rn(rr.z, rr.x), 1.0f);
    float x0 = __fadd_rn(rr.y, __fmul_rn(w0, 0.5f));
    float y0 = __fadd_rn(rr.x, __fmul_rn(h0, 0.5f));
    float tx = __fdiv_rn(dd.x, 10.0f);
    float ty = __fdiv_rn(dd.y, 10.0f);
    float tw = __fdiv_rn(dd.z, 5.0f);
    float th = __fdiv_rn(dd.w, 5.0f);
    float cx = __fadd_rn(__fmul_rn(tx, w0), x0);
    float cy = __fadd_rn(__fmul_rn(ty, h0), y0);
    float ww = __fmul_rn(expf(tw), w0);
    float hh = __fmul_rn(expf(th), h0);
    float xx1 = fminf(fmaxf(__fsub_rn(cx, __fmul_rn(0.5f, ww)), 0.0f), 799.0f);
    float yy1 = fminf(fmaxf(__fsub_rn(cy, __fmul_rn(0.5f, hh)), 0.0f), 799.0f);
    float xx2 = fminf(fmaxf(__fadd_rn(cx, __fmul_rn(0.5f, ww)), 0.0f), 799.0f);
    float yy2 = fminf(fmaxf(__fadd_rn(cy, __fmul_rn(0.5f, hh)), 0.0f), 799.0f);
    return make_float4(yy1, xx1, yy2, xx2);
}

// ---------------------------------------------------------------------------
// Decode/transpose (verified round 6, unchanged).
// ---------------------------------------------------------------------------
#define TILE  16
#define NTILE 63
__global__ __launch_bounds__(256) void decode_kernel(
    const float* __restrict__ rois,
    const float* __restrict__ conf,
    const float* __restrict__ deltas,
    float* __restrict__ scoreT,          // [N][80][1024]
    float* __restrict__ boxT,            // [N][80][1024][4]
    float* __restrict__ outRois)
{
    __shared__ float4 lrois[TILE];
    __shared__ float4 lbox[16][TILE + 1];
    __shared__ float  lsc[16][TILE + 1];

    const int tid  = threadIdx.x;
    const int n    = blockIdx.x / NTILE;
    const int tile = blockIdx.x % NTILE;
    const int b0   = tile * TILE;
    const float4 INERT = make_float4(1.0e9f, 1.0e9f, -1.0e9f, -1.0e9f);

    {
        int gidx = blockIdx.x * 256 + tid;
        if (gidx < N_IMG * B_BOX * 4) outRois[gidx] = rois[gidx];
    }

    if (tid < TILE) {
        int b = b0 + tid;
        lrois[tid] = (b < B_BOX) ? ((const float4*)rois)[n * B_BOX + b]
                                 : make_float4(0.f, 0.f, 0.f, 0.f);
    }
    __syncthreads();

    #pragma unroll
    for (int c0 = 0; c0 < N_CLS; c0 += 16) {
        {
            int bl = tid >> 4, ci = tid & 15;
            int b = b0 + bl, c = c0 + ci;
            float4 bx; float sc;
            if (b < B_BOX) {
                float4 dd = ((const float4*)deltas)[(n * B_BOX + b) * N_CLS + c];
                sc = conf[((size_t)(n * B_BOX + b)) * C1 + c];
                bx = decode_box(lrois[bl], dd);
            } else { bx = INERT; sc = 0.0f; }
            lbox[ci][bl] = bx; lsc[ci][bl] = sc;
        }
        __syncthreads();
        {
            int cc = tid >> 4, bl = tid & 15;
            size_t row = ((size_t)n * N_CLS + c0 + cc) * BPAD + b0 + bl;
            ((float4*)boxT)[row] = lbox[cc][bl];
            scoreT[row] = lsc[cc][bl];
        }
        __syncthreads();
    }

    if (tile == 0) {
        for (int i = tid; i < N_CLS * 16; i += 256) {
            int c = i >> 4, b = 1008 + (i & 15);
            size_t row = ((size_t)n * N_CLS + c) * BPAD + b;
            ((float4*)boxT)[row] = INERT;
            scoreT[row] = 0.0f;
        }
    }
}

// ---------------------------------------------------------------------------
// NMS: one wave per (image, class). Sort (verified) with cheaper exchange
// primitives; scan replaced by batch-parallel greedy — keeps occur in exactly
// the sorted order, so semantics are identical to the verified serial scan.
// ---------------------------------------------------------------------------
template <bool PRE>
__global__ __launch_bounds__(64) void nms_kernel(
    const float* __restrict__ rois,
    const float* __restrict__ conf,
    const float* __restrict__ deltas,
    const float* __restrict__ scoreT,
    const float* __restrict__ boxT,
    float* __restrict__ candScore,       // [N][CAND]
    float* __restrict__ candBox)         // [N][CAND][4]
{
    __shared__ float4 sbox[1024];
    __shared__ u64    skeyS[1024];
    __shared__ float4 sboxS[1024];
    __shared__ float4 keptB[K_MAX];
    __shared__ float  keptA[K_MAX];

    const int n    = blockIdx.x / N_CLS;
    const int c    = blockIdx.x % N_CLS;
    const int lane = threadIdx.x;
    const int base = lane * 16;
    const float4 INERT = make_float4(1.0e9f, 1.0e9f, -1.0e9f, -1.0e9f);

    u64 e[16];

    if (PRE) {
        const size_t row = ((size_t)n * N_CLS + c) * BPAD;
        #pragma unroll
        for (int t = 0; t < 16; t++) {
            const int b = lane + t * 64;               // coalesced
            float4 q = ((const float4*)boxT)[row + b];
            float sc = scoreT[row + b];
            sbox[b] = q;
            unsigned sb = (sc > 0.05f) ? __float_as_uint(sc) : 0u;
            e[t] = ((u64)sb << 32) | (unsigned)(1023 - b);
        }
    } else {
        #pragma unroll
        for (int t = 0; t < 16; t++) {
            const int b = base + t;
            if (b < B_BOX) {
                float4 rr = ((const float4*)rois)[n * B_BOX + b];
                float4 dd = ((const float4*)deltas)[(n * B_BOX + b) * N_CLS + c];
                float score = conf[((size_t)(n * B_BOX + b)) * C1 + c];
                float4 q = decode_box(rr, dd);
                sbox[b] = q;
                unsigned sb = (score > 0.05f) ? __float_as_uint(score) : 0u;
                e[t] = ((u64)sb << 32) | (unsigned)(1023 - b);
            } else {
                sbox[b] = INERT;
                e[t] = (u64)(unsigned)(1023 - b);
            }
        }
    }

    // bitonic sort, descending (verified network)
    ice<1>(e, base, 2);
    ice<2>(e, base, 4);  ice<1>(e, base, 4);
    ice<4>(e, base, 8);  ice<2>(e, base, 8);  ice<1>(e, base, 8);
    ice_all(e, base, 16);
    xce<1>(e, lane, 32);  ice_all(e, base, 32);
    xce<2>(e, lane, 64);  xce<1>(e, lane, 64);  ice_all(e, base, 64);
    xce<4>(e, lane, 128); xce<2>(e, lane, 128); xce<1>(e, lane, 128); ice_all(e, base, 128);
    xce<8>(e, lane, 256); xce<4>(e, lane, 256); xce<2>(e, lane, 256); xce<1>(e, lane, 256);
    ice_all(e, base, 256);
    xce<16>(e, lane, 512); xce<8>(e, lane, 512); xce<4>(e, lane, 512); xce<2>(e, lane, 512);
    xce<1>(e, lane, 512);  ice_all(e, base, 512);
    xce<32>(e, lane, 1024); xce<16>(e, lane, 1024); xce<8>(e, lane, 1024);
    xce<4>(e, lane, 1024);  xce<2>(e, lane, 1024);  xce<1>(e, lane, 1024);
    ice_all(e, base, 1024);

    #pragma unroll
    for (int t = 0; t < 16; t++) skeyS[base + t] = e[t];
    __syncthreads();

    for (int p = lane; p < 1024; p += 64) {
        u64 key = skeyS[p];
        int b = 1023 - (int)(unsigned)(key & 0xffffffffu);
        sboxS[p] = sbox[b];
    }
    __syncthreads();

    // --- phase 4: batch-parallel greedy (exact equivalent of serial scan) ---
    float* myScore = candScore + (size_t)n * CAND + c * K_MAX;
    float* myBox   = candBox   + ((size_t)n * CAND + c * K_MAX) * 4;

    int cnt = 0;
    bool done = false;

    for (int t = 0; t < 16 && !done; t++) {
        const int p = t * 64 + lane;
        const u64    key = skeyS[p];      // coalesced
        const float4 cb  = sboxS[p];
        const bool valid = (key >> 32) != 0;
        const float carea = __fmul_rn(__fsub_rn(cb.z, cb.x), __fsub_rn(cb.w, cb.y));

        // suppression vs keeps from earlier batches (uniform LDS broadcast)
        bool sup = false;
        for (int q = 0; q < cnt; q++) {
            float4 kb = keptB[q];
            float  ka = keptA[q];
            float iy1 = fmaxf(kb.x, cb.x), ix1 = fmaxf(kb.y, cb.y);
            float iy2 = fminf(kb.z, cb.z), ix2 = fminf(kb.w, cb.w);
            float ih  = fmaxf(__fsub_rn(iy2, iy1), 0.0f);
            float iw  = fmaxf(__fsub_rn(ix2, ix1), 0.0f);
            float inter = __fmul_rn(ih, iw);
            float den = fmaxf(__fsub_rn(__fadd_rn(ka, carea), inter), 1e-8f);
            sup = sup || ((double)inter > (double)den * CMP_IOU);
        }

        const u64 vmask = __ballot(valid);
        u64 alive = vmask & __ballot(!sup);

        // in-batch resolution: lowest sorted position first (exact greedy order)
        while (alive != 0) {
            const int j = __ffsll(alive) - 1;
            const float bx = __int_as_float(__builtin_amdgcn_readlane(__float_as_int(cb.x), j));
            const float by = __int_as_float(__builtin_amdgcn_readlane(__float_as_int(cb.y), j));
            const float bz = __int_as_float(__builtin_amdgcn_readlane(__float_as_int(cb.z), j));
            const float bw = __int_as_float(__builtin_amdgcn_readlane(__float_as_int(cb.w), j));
            const float ba = __int_as_float(__builtin_amdgcn_readlane(__float_as_int(carea), j));

            if (lane == j) {
                myScore[cnt] = __uint_as_float((unsigned)(key >> 32));
                ((float4*)myBox)[cnt] = cb;
                keptB[cnt] = cb;
                keptA[cnt] = carea;
            }
            cnt++;
            if (cnt >= K_MAX) { done = true; break; }

            alive &= ~(1ull << j);
            if (alive != 0) {
                float iy1 = fmaxf(bx, cb.x), ix1 = fmaxf(by, cb.y);
                float iy2 = fminf(bz, cb.z), ix2 = fminf(bw, cb.w);
                float ih  = fmaxf(__fsub_rn(iy2, iy1), 0.0f);
                float iw  = fmaxf(__fsub_rn(ix2, ix1), 0.0f);
                float inter = __fmul_rn(ih, iw);
                float den = fmaxf(__fsub_rn(__fadd_rn(ba, carea), inter), 1e-8f);
                bool s2 = (double)inter > (double)den * CMP_IOU;
                alive &= ~__ballot(s2);
            }
        }

        if (vmask != ~0ull) done = true;   // sorted: rest of list is invalid
    }
    for (int q = cnt + lane; q < K_MAX; q += 64) myScore[q] = -1.0f;
}

// ---------------------------------------------------------------------------
// Top-K: exact parallel MSD radix-select (verified round 6, unchanged).
// ---------------------------------------------------------------------------
__global__ __launch_bounds__(256) void topk_kernel(
    const float* __restrict__ candScore,
    const float* __restrict__ candBox,
    float* __restrict__ out)
{
    __shared__ unsigned U[CAND];
    __shared__ int  hist[2048];
    __shared__ int  psum[256];
    __shared__ u64  selK[K_MAX];
    __shared__ int  selQ[K_MAX];
    __shared__ int  nsel, sB, sR, cntv;

    const int n   = blockIdx.x;
    const int tid = threadIdx.x;
    const float* S = candScore + (size_t)n * CAND;

    for (int i = tid; i < CAND; i += 256) {
        float s = S[i];
        U[i] = (s > 0.0f) ? __float_as_uint(s) : 0u;
    }
    if (tid == 0) { nsel = 0; cntv = 0; }
    __syncthreads();

    u64 pref = 0;
    int r = K_MAX;

    #pragma unroll
    for (int pass = 0; pass < 4; pass++) {
        const int shift = 33 - 11 * pass;
        for (int j = tid; j < 2048; j += 256) hist[j] = 0;
        __syncthreads();

        for (int i = tid; i < CAND; i += 256) {
            u64 K = (((u64)U[i]) << 13) | (unsigned)(8191 - i);
            if ((K >> (shift + 11)) == pref)
                atomicAdd(&hist[(int)((K >> shift) & 0x7FF)], 1);
        }
        __syncthreads();

        {
            int g = 0;
            #pragma unroll
            for (int j = 0; j < 8; j++) g += hist[2047 - 8 * tid - j];
            psum[tid] = g;
        }
        __syncthreads();
        for (int off = 1; off < 256; off <<= 1) {
            int v = (tid >= off) ? psum[tid - off] : 0;
            __syncthreads();
            psum[tid] += v;
            __syncthreads();
        }
        {
            int before = (tid > 0) ? psum[tid - 1] : 0;
            if (before < r && psum[tid] >= r) {
                int acc = before;
                #pragma unroll
                for (int j = 0; j < 8; j++) {
                    int b = 2047 - 8 * tid - j;
                    int h = hist[b];
                    acc += h;
                    if (acc >= r) { sB = b; sR = r - (acc - h); break; }
                }
            }
        }
        __syncthreads();
        pref = (pref << 11) | (unsigned)sB;
        r = sR;
        __syncthreads();
    }
    const u64 T64 = pref;

    for (int i = tid; i < CAND; i += 256) {
        u64 K = (((u64)U[i]) << 13) | (unsigned)(8191 - i);
        if (K >= T64) {
            int s = atomicAdd(&nsel, 1);
            selK[s] = K; selQ[s] = i;
        }
    }
    __syncthreads();

    if (tid < K_MAX) {
        const u64 Ki = selK[tid];
        int rank = 0;
        for (int j = 0; j < K_MAX; j++) rank += (selK[j] > Ki) ? 1 : 0;

        const unsigned u = (unsigned)(Ki >> 13);
        const int q = selQ[tid];
        const bool valid = (u != 0);
        float4 bx = make_float4(0.f, 0.f, 0.f, 0.f);
        if (valid) bx = ((const float4*)candBox)[(size_t)n * CAND + q];

        ((float4*)out)[n * K_MAX + rank] = bx;
        out[N_IMG * K_MAX * 4 + n * K_MAX + rank] = valid ? __uint_as_float(u) : 0.0f;
        out[N_IMG * K_MAX * 5 + n * K_MAX + rank] = valid ? (float)(q / K_MAX) : 0.0f;
        if (valid) atomicAdd(&cntv, 1);
    }
    __syncthreads();
    if (tid == 0) out[N_IMG * K_MAX * 6 + n] = (float)cntv;
}

extern "C" void kernel_launch(void* const* d_in, const int* in_sizes, int n_in,
                              void* d_out, int out_size, void* d_ws, size_t ws_size,
                              hipStream_t stream) {
    const float* rois   = (const float*)d_in[0];   // [8][1000][4]
    const float* conf   = (const float*)d_in[1];   // [8][1000][81]
    const float* deltas = (const float*)d_in[2];   // [8][1000][320]
    float* out = (float*)d_out;                    // 36808 floats
    float* ws  = (float*)d_ws;

    float* candScore = ws;                                      // 64000 f
    float* candBox   = candScore + (size_t)N_IMG * CAND;        // 256000 f
    float* scoreT    = candBox + (size_t)N_IMG * CAND * 4;      // 655360 f
    float* boxT      = scoreT + (size_t)N_IMG * N_CLS * BPAD;   // 2621440 f
    const size_t needed = ((size_t)N_IMG * CAND * 5
                         + (size_t)N_IMG * N_CLS * BPAD * 5) * sizeof(float);

    if (ws_size >= needed) {
        decode_kernel<<<N_IMG * NTILE, 256, 0, stream>>>(
            rois, conf, deltas, scoreT, boxT, out + 4808);
        nms_kernel<true><<<N_IMG * N_CLS, 64, 0, stream>>>(
            rois, conf, deltas, scoreT, boxT, candScore, candBox);
        topk_kernel<<<N_IMG, 256, 0, stream>>>(candScore, candBox, out);
    } else {
        nms_kernel<false><<<N_IMG * N_CLS, 64, 0, stream>>>(
            rois, conf, deltas, nullptr, nullptr, candScore, candBox);
        topk_kernel<<<N_IMG, 256, 0, stream>>>(candScore, candBox, out);
        hipMemcpyAsync(out + 4808, rois,
                       (size_t)N_IMG * B_BOX * 4 * sizeof(float),
                       hipMemcpyDeviceToDevice, stream);
    }
}